// Round 13
// baseline (362.213 us; speedup 1.0000x reference)
//
#include <hip/hip_runtime.h>
#include <hip/hip_bf16.h>
#include <math.h>

#define EMBED 1024
#define FFN   4096
#define NW    8
#define MTOT  32768   // 16*2048

#define BM 128
#define BN 128
#define BK 64
#define NT (FFN / BK)   // 64 K-tiles

#define STRIP 128
#define KPT   8

typedef __attribute__((ext_vector_type(8)))  short          short8v;
typedef __attribute__((ext_vector_type(8)))  unsigned short ushort8v;
typedef __attribute__((ext_vector_type(4)))  float          f32x4;
typedef __attribute__((ext_vector_type(16))) float          f32x16;

typedef __attribute__((address_space(1))) void gvoid_t;
typedef __attribute__((address_space(3))) void svoid_t;

static __device__ __forceinline__ unsigned short bf16bits(float f) {
    __hip_bfloat16 h = __float2bfloat16(f);
    return *reinterpret_cast<unsigned short*>(&h);
}

// ---------------- W2 f32 -> bf16 (once, into ws) ----------------
__global__ __launch_bounds__(256) void cvtW2_kernel(const float* __restrict__ W2,
                                                    __hip_bfloat16* __restrict__ Bw) {
    const long i0 = ((long)blockIdx.x * 256 + threadIdx.x) * 8;
    const float4 a = *(const float4*)(W2 + i0);
    const float4 b = *(const float4*)(W2 + i0 + 4);
    float fs[8] = {a.x, a.y, a.z, a.w, b.x, b.y, b.z, b.w};
    ushort8v v;
#pragma unroll
    for (int t = 0; t < 8; ++t) v[t] = bf16bits(fs[t]);
    *reinterpret_cast<ushort8v*>(Bw + i0) = v;
}

// ---------------- producer: h[m,k] = relu(b1[k] + qz[m,:]·W1[k,:]) ----------------
__global__ __launch_bounds__(256) void hprod2_kernel(
    const float* __restrict__ x, const float* __restrict__ theta,
    const float* __restrict__ W1, const float* __restrict__ b1,
    __hip_bfloat16* __restrict__ h, int m0)
{
    __shared__ float qz_lds[STRIP][NW];
    const int tid   = threadIdx.x;
    const int khalf = blockIdx.x & 1;
    const int strip = blockIdx.x >> 1;
    const int k0    = khalf * 2048 + tid * KPT;

    float w1r[KPT][NW];
    float b1r[KPT];
#pragma unroll
    for (int i = 0; i < KPT; ++i) {
        const float4 a = *(const float4*)(W1 + (long)(k0 + i) * NW);
        const float4 b = *(const float4*)(W1 + (long)(k0 + i) * NW + 4);
        w1r[i][0] = a.x; w1r[i][1] = a.y; w1r[i][2] = a.z; w1r[i][3] = a.w;
        w1r[i][4] = b.x; w1r[i][5] = b.y; w1r[i][6] = b.z; w1r[i][7] = b.w;
        b1r[i] = b1[k0 + i];
    }

    if (tid < STRIP) {
        const long m = (long)m0 + (long)strip * STRIP + tid;
        const float* xr = x + m * (long)EMBED;
#pragma unroll
        for (int w = 0; w < NW; ++w)
            qz_lds[tid][w] = cosf(xr[w]) * cosf(theta[w]);
    }
    __syncthreads();

    __hip_bfloat16* hp = h + ((long)strip * STRIP) * FFN + k0;
    for (int r = 0; r < STRIP; ++r) {
        float q[NW];
#pragma unroll
        for (int w = 0; w < NW; ++w) q[w] = qz_lds[r][w];
        ushort8v hv;
#pragma unroll
        for (int i = 0; i < KPT; ++i) {
            float acc = b1r[i];
#pragma unroll
            for (int w = 0; w < NW; ++w) acc = fmaf(q[w], w1r[i][w], acc);
            hv[i] = bf16bits(fmaxf(acc, 0.0f));
        }
        *reinterpret_cast<ushort8v*>(hp + (long)r * FFN) = hv;
    }
}

// ---------------- GEMM v13: R12 structure + 32x32x16 MFMA ----------------
// out[M,1024] = h[M,4096] @ W2bf[1024,4096]^T + b2
// R12 confirmed: occupancy (120 total regs -> ~3.2 blk/CU) is the mechanism;
// 305us ~ 900 TF = m97-family plateau. v13 swaps the MFMA shape only:
// 32x32x16 runs the same FLOPs at 2382 TF ubench vs 2075 (16x16), halving
// instruction count (16/tile vs 32) at identical LDS bytes and acc budget
// (2x2 tiles x 16 f32 = 64 AGPR). Operand map: row/col=lane&31,
// k=(lane>>5)*8+j (16B k-contiguous -> same LDS layout + XOR swizzle,
// still <=2-way = free). C/D: col=lane&31, row=(reg&3)+8*(reg>>2)+4*(lane>>5)
// (m74/m101-verified). Everything else byte-identical to R12.
__global__ __launch_bounds__(256, 4) void gemm13_kernel(
    const __hip_bfloat16* __restrict__ A,   // [rows][FFN] chunk-local h
    const __hip_bfloat16* __restrict__ Bw,  // [EMBED][FFN] W2 bf16
    const float* __restrict__ b2,
    float* __restrict__ out, long m0, int nPm)
{
    __shared__ __align__(16) __hip_bfloat16 As[BM * BK];  // 16 KB
    __shared__ __align__(16) __hip_bfloat16 Bs[BN * BK];  // 16 KB

    const int tid = threadIdx.x, wid = tid >> 6, lane = tid & 63;
    const int l31 = lane & 31, l5 = lane >> 5;
    const int wr = wid >> 1, wc = wid & 1;          // 2M x 2N wave grid

    // XCD map: bid = xcd + 8*j; per pm, 8 pn back-to-back on one XCD.
    const int xcd = blockIdx.x & 7, j = blockIdx.x >> 3;
    const int pn  = j & 7;
    const int pm  = xcd * (nPm >> 3) + (j >> 3);

    // staging: 8 threads/row (8x16B=128B row); 4 sweeps of 32 rows.
    // Global source col pre-XORed by row&7 -> linear LDS + XOR'd read, 0 conf.
    const int srow  = tid >> 3;                     // 0..31
    const int colsw = ((tid & 7) ^ (srow & 7)) * 8;

    const __hip_bfloat16* Ag = A  + (long)(pm * BM + srow) * FFN + colsw;
    const __hip_bfloat16* Bg = Bw + (long)(pn * BN + srow) * FFN + colsw;

    f32x16 acc[2][2];
#pragma unroll
    for (int i = 0; i < 2; ++i)
#pragma unroll
        for (int jj = 0; jj < 2; ++jj)
#pragma unroll
            for (int r = 0; r < 16; ++r) acc[i][jj][r] = 0.f;

    const int rx = (lane & 7) << 3;   // read-side elem XOR; row&7 == lane&7

    for (int t = 0; t < NT; ++t) {
        __syncthreads();   // previous tile's reads complete before overwrite
#pragma unroll
        for (int s = 0; s < 4; ++s) {
            __builtin_amdgcn_global_load_lds(
                (gvoid_t*)(Ag + (long)(s * 32) * FFN + t * BK),
                (svoid_t*)(&As[(s * 32 + wid * 8) * BK]), 16, 0, 0);
            __builtin_amdgcn_global_load_lds(
                (gvoid_t*)(Bg + (long)(s * 32) * FFN + t * BK),
                (svoid_t*)(&Bs[(s * 32 + wid * 8) * BK]), 16, 0, 0);
        }
        __syncthreads();   // tile resident (vmcnt0 drain; sibling blocks hide)

        // ks-major: 4 K-slices of 16; per slice 2 bv + 2 av reads, 4 MFMA
#pragma unroll
        for (int ks = 0; ks < 4; ++ks) {
            const int kcol = ks * 16 + l5 * 8;
            short8v bv[2];
#pragma unroll
            for (int ni = 0; ni < 2; ++ni) {
                const int row = wc * 64 + ni * 32 + l31;
                bv[ni] = *reinterpret_cast<const short8v*>(
                    &Bs[row * BK + (kcol ^ rx)]);
            }
#pragma unroll
            for (int mi = 0; mi < 2; ++mi) {
                const int row = wr * 64 + mi * 32 + l31;
                const short8v av = *reinterpret_cast<const short8v*>(
                    &As[row * BK + (kcol ^ rx)]);
#pragma unroll
                for (int ni = 0; ni < 2; ++ni)
                    acc[mi][ni] = __builtin_amdgcn_mfma_f32_32x32x16_bf16(
                        av, bv[ni], acc[mi][ni], 0, 0, 0);
            }
        }
    }

    // epilogue: + b2, f32 store.
    // C/D (32x32): col=lane&31, row=(reg&3)+8*(reg>>2)+4*(lane>>5)
    const int gn0 = pn * BN + wc * 64;
    float bias[2];
#pragma unroll
    for (int ni = 0; ni < 2; ++ni) bias[ni] = b2[gn0 + ni * 32 + l31];
    const long gm0 = m0 + (long)pm * BM + wr * 64;
#pragma unroll
    for (int mi = 0; mi < 2; ++mi)
#pragma unroll
        for (int ni = 0; ni < 2; ++ni)
#pragma unroll
            for (int r = 0; r < 16; ++r) {
                const long row = gm0 + mi * 32 + (r & 3) + 8 * (r >> 2) + 4 * l5;
                out[row * EMBED + gn0 + ni * 32 + l31] = acc[mi][ni][r] + bias[ni];
            }
}

extern "C" void kernel_launch(void* const* d_in, const int* in_sizes, int n_in,
                              void* d_out, int out_size, void* d_ws, size_t ws_size,
                              hipStream_t stream)
{
    const float* x     = (const float*)d_in[0];
    const float* theta = (const float*)d_in[1];
    const float* W1    = (const float*)d_in[2];
    const float* b1    = (const float*)d_in[3];
    const float* W2    = (const float*)d_in[4];
    const float* b2    = (const float*)d_in[5];
    float* out = (float*)d_out;

    const size_t w2b = (size_t)EMBED * FFN * 2;          // 8.4 MB bf16 W2
    __hip_bfloat16* Bw = (__hip_bfloat16*)d_ws;
    __hip_bfloat16* h  = (__hip_bfloat16*)((char*)d_ws + w2b);
    const size_t avail = ws_size > w2b ? ws_size - w2b : 0;

    // chunk = 16384 rows: h-chunk (134MB) stays L3-resident between hprod and
    // gemm (hprod writes retire on-die; gemm A-reads hit L3), while the gemm
    // grid stays 1024 blocks = 4 blk/CU-slots (occupancy mechanism intact).
    long chunk = (long)((avail / ((size_t)FFN * 2)) & ~2047UL);
    if (chunk > 16384) chunk = 16384;
    if (chunk < 2048)  chunk = 2048;

    cvtW2_kernel<<<(EMBED * FFN) / 2048, 256, 0, stream>>>(W2, Bw);

    for (long m0 = 0; m0 < MTOT; m0 += chunk) {
        const long rows = (MTOT - m0 < chunk) ? (MTOT - m0) : chunk;
        hprod2_kernel<<<(int)((rows / STRIP) * 2), 256, 0, stream>>>(
            x, theta, W1, b1, h, (int)m0);
        const int nPm = (int)(rows / BM);                 // multiple of 16
        gemm13_kernel<<<nPm * 8, 256, 0, stream>>>(h, Bw, b2, out, m0, nPm);
    }
}